// Round 8
// baseline (250.179 us; speedup 1.0000x reference)
//
#include <hip/hip_runtime.h>
#include <cstdint>

// Problem: out = inputs @ W  (softmax over a constant axis is uniform; GAT collapses to the GEMM)
// inputs: (131072, 256) fp32, W: (256,256) fp32, out: (131072, 256) fp32.
//
// V7r: persistent full-N block (resubmission; round-7 bench was an infra
// failure — container acquisition — not a kernel verdict).
// 256 blocks (1/CU), 1024 threads (16 waves = 4M x 4N).
// - Bs = full W (256n x 256k bf16, XOR-swizzled) resident: 128 KB, staged ONCE.
//   Full N => A read exactly once (V5/V6 read it twice, once per N-half).
// - As = single 128x64 bf16 tile (16 KB). LDS total 144 KB (<160 KB/CU).
// - Flat 16-step stream (4 M-tiles x 4 K-tiles): loads for step s+2 issued at
//   step s (depth-2 reg lookahead); tile stores issue MID-STREAM right after the
//   tile's last MFMA, draining concurrently with the next tile's loads.
// - Barriers are raw s_barrier + lgkmcnt(0) only (loads/stores in flight across).
//
// V6 post-mortem: 4 sequential blocks/CU, stores bunched in a per-block epilogue
// that cannot overlap the next block's loads (1 block/CU) -> read/write streams
// serialized -> 2.5 TB/s while fillBuffer hits 6.6 TB/s on the same capture.

static constexpr int MTOT = 64 * 2048;   // 131072
static constexpr int KDIM = 256;
static constexpr int NDIM = 256;

typedef __bf16 bf16x8 __attribute__((ext_vector_type(8)));
typedef float f32x4 __attribute__((ext_vector_type(4)));

__device__ __forceinline__ uint32_t f2bf_pk(float a, float b) {
    // pack two fp32 -> two bf16 (RNE), lo = a, hi = b
    uint32_t ua = __float_as_uint(a);
    uint32_t ub = __float_as_uint(b);
    ua = ua + 0x7fffu + ((ua >> 16) & 1u);
    ub = ub + 0x7fffu + ((ub >> 16) & 1u);
    return (ua >> 16) | (ub & 0xffff0000u);
}

// --- kernel 1: W (k-major fp32) -> Wt (n-major bf16) in workspace -----------
__global__ void wt_transpose(const float* __restrict__ W, unsigned short* __restrict__ Wt) {
    int n = blockIdx.x;    // 256 blocks
    int k = threadIdx.x;   // 256 threads
    float v = W[k * NDIM + n];           // uncoalesced read; W is 256 KB, L2 absorbs
    uint32_t u = __float_as_uint(v);
    u = u + 0x7fffu + ((u >> 16) & 1u);
    Wt[n * KDIM + k] = (unsigned short)(u >> 16);   // coalesced write
}

// --- kernel 2: persistent full-N GEMM ----------------------------------------
__global__ __launch_bounds__(1024, 1)
void gat_gemm(const float* __restrict__ A, const unsigned short* __restrict__ Wt,
              float* __restrict__ C) {
    // Bs: 256 n-rows x 256 k bf16, row stride 512 B, byte ^= (n&7)<<4   (128 KB)
    // As: 128 rows x 64 k bf16,   row stride 128 B, byte ^= (row&7)<<4  (16 KB)
    __shared__ alignas(16) unsigned short Bs[256 * 256];
    __shared__ alignas(16) unsigned short As[128 * 64];

    const int tid  = threadIdx.x;
    const int lane = tid & 63;
    const int wave = tid >> 6;       // 0..15
    const int l15  = lane & 15;
    const int quad = lane >> 4;
    const int wm   = wave & 3;       // 4 M-slots x 32 rows   (= 128)
    const int wn   = wave >> 2;      // 4 N-slots x 64 cols   (= 256)

    const size_t bbase = (size_t)blockIdx.x * 512;   // block's 512 rows (4 tiles x 128)

    // A staging: step tile = 128 rows x 64 floats = 2048 16B-chunks.
    // Thread t takes chunks {t, t+1024}: rows (t>>4) and (t>>4)+64, float col (t&15)*4.
    // Per load instruction a wave reads 1 KB contiguous (perfect coalescing).
    const int arow = tid >> 4;          // 0..63
    const int acol = (tid & 15) * 4;    // float col in the 64-float row
    const int as8  = (tid & 15) * 8;    // byte col of the converted 8B piece

    f32x4 acc[2][4];
#pragma unroll
    for (int i = 0; i < 2; ++i)
#pragma unroll
        for (int j = 0; j < 4; ++j)
            acc[i][j] = (f32x4)0.0f;

    auto issueA = [&](int s, float4 (&R)[2]) {
        const float* ap = A + (bbase + (size_t)(s >> 2) * 128) * KDIM + (s & 3) * 64 + acol;
        R[0] = *(const float4*)(ap + (size_t)arow * KDIM);
        R[1] = *(const float4*)(ap + (size_t)(arow + 64) * KDIM);
    };
    auto writeA = [&](float4 (&R)[2]) {
        uint2 w0, w1;
        w0.x = f2bf_pk(R[0].x, R[0].y); w0.y = f2bf_pk(R[0].z, R[0].w);
        w1.x = f2bf_pk(R[1].x, R[1].y); w1.y = f2bf_pk(R[1].z, R[1].w);
        const int r0 = arow, r1 = arow + 64;
        *(uint2*)((char*)As + r0 * 128 + (as8 ^ ((r0 & 7) << 4))) = w0;
        *(uint2*)((char*)As + r1 * 128 + (as8 ^ ((r1 & 7) << 4))) = w1;
    };
    auto compute = [&](int kt) {
#pragma unroll
        for (int ks = 0; ks < 2; ++ks) {
            bf16x8 af[2];
#pragma unroll
            for (int i = 0; i < 2; ++i) {
                const int row = wm * 32 + i * 16 + l15;
                af[i] = *(const bf16x8*)((const char*)As + row * 128 +
                          ((ks * 64 + quad * 16) ^ ((row & 7) << 4)));
            }
#pragma unroll
            for (int j = 0; j < 4; ++j) {
                const int n = wn * 64 + j * 16 + l15;
                bf16x8 bf = *(const bf16x8*)((const char*)Bs + n * 512 +
                              ((kt * 128 + ks * 64 + quad * 16) ^ ((n & 7) << 4)));
#pragma unroll
                for (int i = 0; i < 2; ++i)
                    acc[i][j] = __builtin_amdgcn_mfma_f32_16x16x32_bf16(af[i], bf, acc[i][j], 0, 0, 0);
            }
        }
    };
    // Non-draining barrier: own LDS ops done (lgkmcnt(0)); global loads/stores
    // stay in flight (no vmcnt(0)).
    auto wavebar = [&]() {
        asm volatile("s_waitcnt lgkmcnt(0)" ::: "memory");
        __builtin_amdgcn_s_barrier();
        asm volatile("" ::: "memory");
    };

    // ---- prologue ----------------------------------------------------------
    // Issue B-stage loads (oldest), then A steps 0,1; Bs writes wait vmcnt(4),
    // As write waits vmcnt(2) -- step-1 loads never drained.
    uint4 bv[8];
#pragma unroll
    for (int c = 0; c < 8; ++c) {
        const int idx = c * 1024 + tid;           // n = idx>>5, kc = idx&31 (16B units)
        bv[c] = *(const uint4*)(Wt + (size_t)(idx >> 5) * KDIM + (idx & 31) * 8);
    }
    float4 R0[2], R1[2];
    issueA(0, R0);
    issueA(1, R1);
#pragma unroll
    for (int c = 0; c < 8; ++c) {
        const int idx = c * 1024 + tid;
        const int n = idx >> 5, kc = idx & 31;
        *(uint4*)((char*)Bs + n * 512 + ((kc * 16) ^ ((n & 7) << 4))) = bv[c];
    }
    writeA(R0);
    wavebar();

    // ---- flat 16-step stream: s = (mtile<<2) | ktile ------------------------
    // iter s: issue s+2 -> R[s&1]; MFMA step s; (tile end: store acc, re-zero);
    // barrier; ds_write step s+1 from R[(s+1)&1]; barrier.
#pragma unroll
    for (int s = 0; s < 16; ++s) {
        if (s < 14) {
            if (s & 1) issueA(s + 2, R1); else issueA(s + 2, R0);
        }
        compute(s & 3);

        if ((s & 3) == 3) {
            // tile (s>>2) finished: store mid-stream (drains under next tile's loads)
            const size_t mb = bbase + (size_t)(s >> 2) * 128 + wm * 32;
#pragma unroll
            for (int i = 0; i < 2; ++i) {
#pragma unroll
                for (int r = 0; r < 4; ++r) {
                    float* cp = C + (mb + i * 16 + quad * 4 + r) * NDIM + wn * 64 + l15;
#pragma unroll
                    for (int j = 0; j < 4; ++j)
                        cp[j * 16] = acc[i][j][r];
                }
            }
#pragma unroll
            for (int i = 0; i < 2; ++i)
#pragma unroll
                for (int j = 0; j < 4; ++j)
                    acc[i][j] = (f32x4)0.0f;
        }

        if (s < 15) {
            wavebar();                               // all waves done reading As
            if (s & 1) writeA(R0); else writeA(R1);  // step s+1 data
            wavebar();                               // As ready for step s+1
        }
    }
}

extern "C" void kernel_launch(void* const* d_in, const int* in_sizes, int n_in,
                              void* d_out, int out_size, void* d_ws, size_t ws_size,
                              hipStream_t stream) {
    (void)in_sizes; (void)n_in; (void)out_size; (void)ws_size;
    const float* inputs = (const float*)d_in[0];
    const float* W      = (const float*)d_in[1];
    // d_in[2] ('a') is mathematically unused: softmax over a constant axis is uniform,
    // so the output is exactly inputs @ W.
    unsigned short* Wt = (unsigned short*)d_ws;     // 256*256*2 = 128 KB scratch
    float* out = (float*)d_out;

    hipLaunchKernelGGL(wt_transpose, dim3(NDIM), dim3(KDIM), 0, stream, W, Wt);
    // 256 persistent blocks (1/CU), each owns 512 rows = 4 M-tiles of 128
    hipLaunchKernelGGL(gat_gemm, dim3(MTOT / 512), dim3(1024), 0, stream, inputs, Wt, out);
}